// Round 6
// baseline (830.427 us; speedup 1.0000x reference)
//
#include <hip/hip_runtime.h>

// ======================= compile-time Wigner-3j tables =======================
// Mirrors the Python reference exactly (double precision, then cast to f32,
// with pw = sqrt(2*l3+1) folded in).

constexpr double cfact(int n) { double r = 1.0; for (int i = 2; i <= n; ++i) r *= i; return r; }

constexpr double csqrt(double x) {
  double g = x > 1.0 ? x : 1.0;
  for (int it = 0; it < 64; ++it) g = 0.5 * (g + x / g);
  return g;
}

constexpr double su2_cg(int j1, int j2, int j3, int m1, int m2, int m3) {
  if (m3 != m1 + m2) return 0.0;
  int vmin = -j1 + j2 + m3;
  if (-j1 + m1 > vmin) vmin = -j1 + m1;
  if (0 > vmin) vmin = 0;
  int vmax = j2 + j3 + m1;
  if (j3 - j1 + j2 < vmax) vmax = j3 - j1 + j2;
  if (j3 + m3 < vmax) vmax = j3 + m3;
  double pref = csqrt((2.0 * j3 + 1.0) * cfact(j3 + j1 - j2) * cfact(j3 - j1 + j2) *
                      cfact(j1 + j2 - j3) * cfact(j3 + m3) * cfact(j3 - m3) /
                      (cfact(j1 + j2 + j3 + 1) * cfact(j1 - m1) * cfact(j1 + m1) *
                       cfact(j2 - m2) * cfact(j2 + m2)));
  double s = 0.0;
  for (int v = vmin; v <= vmax; ++v) {
    double term = cfact(j2 + j3 + m1 - v) * cfact(j1 - m1 + v) /
                  (cfact(v) * cfact(j3 - j1 + j2 - v) * cfact(j3 + m3 - v) *
                   cfact(j1 - j2 - m3 + v));
    if ((v + j2 + m2) & 1) term = -term;
    s += term;
  }
  return pref * s;
}

struct cplx { double re, im; };
constexpr cplx cmul(cplx a, cplx b) { return {a.re * b.re - a.im * b.im, a.re * b.im + a.im * b.re}; }
constexpr cplx conjc(cplx a) { return {a.re, -a.im}; }

template <int L> struct QMat { cplx q[2 * L + 1][2 * L + 1]; };

template <int L>
constexpr QMat<L> make_q() {
  QMat<L> Q{};
  const double rs2 = 1.0 / csqrt(2.0);
  for (int m = -L; m < 0; ++m) {
    Q.q[L + m][L - m] = cplx{rs2, 0.0};   // q[l+m, l+|m|] = 1/sqrt2
    Q.q[L + m][L + m] = cplx{0.0, -rs2};  // q[l+m, l-|m|] = -i/sqrt2
  }
  Q.q[L][L] = cplx{1.0, 0.0};
  for (int m = 1; m <= L; ++m) {
    double sgn = (m & 1) ? -1.0 : 1.0;
    Q.q[L + m][L + m] = cplx{sgn * rs2, 0.0};
    Q.q[L + m][L - m] = cplx{0.0, sgn * rs2};
  }
  cplx f{1.0, 0.0};                       // (-i)^L
  for (int t = 0; t < L; ++t) f = cmul(f, cplx{0.0, -1.0});
  for (int a = 0; a < 2 * L + 1; ++a)
    for (int b = 0; b < 2 * L + 1; ++b) Q.q[a][b] = cmul(f, Q.q[a][b]);
  return Q;
}

template <int L1, int L2, int L3> struct W3T { float c[2 * L1 + 1][2 * L2 + 1][2 * L3 + 1]; };

template <int L1, int L2, int L3>
constexpr W3T<L1, L2, L3> make_w3() {
  constexpr int d1 = 2 * L1 + 1, d2 = 2 * L2 + 1, d3 = 2 * L3 + 1;
  double Cre[d1][d2][d3]{};
  for (int i = 0; i < d1; ++i)
    for (int j = 0; j < d2; ++j)
      for (int k = 0; k < d3; ++k)
        Cre[i][j][k] = su2_cg(L1, L2, L3, -L1 + i, -L2 + j, -L3 + k);
  QMat<L1> Q1 = make_q<L1>();
  QMat<L2> Q2 = make_q<L2>();
  QMat<L3> Q3 = make_q<L3>();
  double Cr[d1][d2][d3]{};
  // Cr[j,l,m] = Re( sum_{i,k,n} Q1[i,j] Q2[k,l] conj(Q3[n,m]) C[i,k,n] )
  for (int j = 0; j < d1; ++j)
    for (int l = 0; l < d2; ++l)
      for (int m = 0; m < d3; ++m) {
        cplx s{0.0, 0.0};
        for (int i = 0; i < d1; ++i)
          for (int k = 0; k < d2; ++k)
            for (int n = 0; n < d3; ++n) {
              cplx t = cmul(Q1.q[i][j], Q2.q[k][l]);
              t = cmul(t, conjc(Q3.q[n][m]));
              s.re += t.re * Cre[i][k][n];
              s.im += t.im * Cre[i][k][n];
            }
        Cr[j][l][m] = s.re;
      }
  double nrm = 0.0;
  for (int i = 0; i < d1; ++i)
    for (int j = 0; j < d2; ++j)
      for (int k = 0; k < d3; ++k) nrm += Cr[i][j][k] * Cr[i][j][k];
  nrm = csqrt(nrm);
  double pw = csqrt(2.0 * L3 + 1.0);
  W3T<L1, L2, L3> out{};
  for (int i = 0; i < d1; ++i)
    for (int j = 0; j < d2; ++j)
      for (int k = 0; k < d3; ++k) out.c[i][j][k] = (float)((Cr[i][j][k] / nrm) * pw);
  return out;
}

// 15 instructions, in reference order (each evaluated as its own constant expr)
constexpr auto cW000 = make_w3<0, 0, 0>();
constexpr auto cW011 = make_w3<0, 1, 1>();
constexpr auto cW022 = make_w3<0, 2, 2>();
constexpr auto cW101 = make_w3<1, 0, 1>();
constexpr auto cW110 = make_w3<1, 1, 0>();
constexpr auto cW111 = make_w3<1, 1, 1>();
constexpr auto cW112 = make_w3<1, 1, 2>();
constexpr auto cW121 = make_w3<1, 2, 1>();
constexpr auto cW122 = make_w3<1, 2, 2>();
constexpr auto cW202 = make_w3<2, 0, 2>();
constexpr auto cW211 = make_w3<2, 1, 1>();
constexpr auto cW212 = make_w3<2, 1, 2>();
constexpr auto cW220 = make_w3<2, 2, 0>();
constexpr auto cW221 = make_w3<2, 2, 1>();
constexpr auto cW222 = make_w3<2, 2, 2>();

// ======================= device kernel =======================

#define UNROLL _Pragma("unroll")

// Fully-unrolled per-instruction contraction. Coefficients fold to immediates;
// zero coefficients are dead-code-eliminated at compile time.
#define DO_INSTR(W, L1v, L2v, L3v, OO, T)                                   \
  do {                                                                      \
    constexpr int D1 = 2 * (L1v) + 1, D2 = 2 * (L2v) + 1, D3 = 2 * (L3v) + 1; \
    constexpr int S1 = ((L1v) == 0 ? 0 : ((L1v) == 1 ? 1 : 4));             \
    constexpr int S2 = ((L2v) == 0 ? 0 : ((L2v) == 1 ? 1 : 4));             \
    float o[D3];                                                            \
    UNROLL for (int k = 0; k < D3; ++k) o[k] = 0.0f;                        \
    UNROLL for (int i = 0; i < D1; ++i) {                                   \
      UNROLL for (int j = 0; j < D2; ++j) {                                 \
        const float p = x1v[S1 + i] * yv[S2 + j];                           \
        UNROLL for (int k = 0; k < D3; ++k) {                               \
          if (W.c[i][j][k] != 0.0f) o[k] = fmaf(W.c[i][j][k], p, o[k]);     \
        }                                                                   \
      }                                                                     \
    }                                                                       \
    const float ww = wv[T];                                                 \
    UNROLL for (int k = 0; k < D3; ++k) op[(OO) + u * D3 + k] = ww * o[k];  \
  } while (0)

__global__ __launch_bounds__(256) void tp_kernel(const float* __restrict__ in1,
                                                 const float* __restrict__ in2,
                                                 const float* __restrict__ wgt,
                                                 float* __restrict__ out, int Bn) {
  const int u = threadIdx.x & 63;                  // mul index (lane)
  const int b = blockIdx.x * 4 + (threadIdx.x >> 6);  // batch row (wave)
  if (b >= Bn) return;

  const float* __restrict__ x1p = in1 + (size_t)b * 576;
  const float* __restrict__ yp  = in2 + (size_t)b * 9;
  const float* __restrict__ wp  = wgt + (size_t)b * 960;
  float* __restrict__ op        = out + (size_t)b * 3264;

  float x1v[9], yv[9], wv[15];
  x1v[0] = x1p[u];                                  // l=0 block
  UNROLL for (int i = 0; i < 3; ++i) x1v[1 + i] = x1p[64 + u * 3 + i];   // l=1
  UNROLL for (int i = 0; i < 5; ++i) x1v[4 + i] = x1p[256 + u * 5 + i];  // l=2
  UNROLL for (int j = 0; j < 9; ++j) yv[j] = yp[j];                       // broadcast
  UNROLL for (int t = 0; t < 15; ++t) wv[t] = wp[t * 64 + u];             // coalesced

  //        table   l1 l2 l3   out_off  instr
  DO_INSTR(cW000, 0, 0, 0,    0,  0);
  DO_INSTR(cW011, 0, 1, 1,   64,  1);
  DO_INSTR(cW022, 0, 2, 2,  256,  2);
  DO_INSTR(cW101, 1, 0, 1,  576,  3);
  DO_INSTR(cW110, 1, 1, 0,  768,  4);
  DO_INSTR(cW111, 1, 1, 1,  832,  5);
  DO_INSTR(cW112, 1, 1, 2, 1024,  6);
  DO_INSTR(cW121, 1, 2, 1, 1344,  7);
  DO_INSTR(cW122, 1, 2, 2, 1536,  8);
  DO_INSTR(cW202, 2, 0, 2, 1856,  9);
  DO_INSTR(cW211, 2, 1, 1, 2176, 10);
  DO_INSTR(cW212, 2, 1, 2, 2368, 11);
  DO_INSTR(cW220, 2, 2, 0, 2688, 12);
  DO_INSTR(cW221, 2, 2, 1, 2752, 13);
  DO_INSTR(cW222, 2, 2, 2, 2944, 14);
}

// ======================= host launch =======================

extern "C" void kernel_launch(void* const* d_in, const int* in_sizes, int n_in,
                              void* d_out, int out_size, void* d_ws, size_t ws_size,
                              hipStream_t stream) {
  const float* in1 = (const float*)d_in[0];
  const float* in2 = (const float*)d_in[1];
  const float* wgt = (const float*)d_in[2];
  float* out = (float*)d_out;
  const int Bn = in_sizes[0] / 576;  // 50000
  const int blocks = (Bn + 3) / 4;   // 4 batch rows (waves) per 256-thread block
  tp_kernel<<<blocks, 256, 0, stream>>>(in1, in2, wgt, out, Bn);
}